// Round 2
// baseline (446.307 us; speedup 1.0000x reference)
//
#include <hip/hip_runtime.h>
#include <hip/hip_bf16.h>
#include <math.h>

// Problem dims (fixed by reference):
//   thing_map   [1, 80, 128, 256]  fp32
//   kernel_space[1,256, 128, 256]  fp32
//   embeddings  [1,256, 256, 512]  fp32
// Outputs (concat, fp32): thing_masks [1,50,256,512] | scores [1,50] | cats [1,50]

constexpr int C   = 80;
constexpr int H   = 128;
constexpr int W   = 256;
constexpr int HW  = H * W;            // 32768
constexpr int CHW = C * HW;           // 2,621,440
constexpr int D   = 256;
constexpr int NPIX = 256 * 512;       // 131072
constexpr int K   = 50;
constexpr int KP  = 52;               // padded k count (13 float4 per d-row)
constexpr int NBINS = 4096;
constexpr int MAXCAND = 8192;
constexpr int SEL_CAP = 4096;
constexpr int MASK_ELEMS = K * NPIX;  // 6,553,600

// Peak compact-list capacity. Strict 3x3-max peaks form an independent set in
// the king graph -> density <= 1/4 (ties could in theory exceed; guarded).
constexpr int CAP = CHW / 4;          // 655,360

// ws layout (units: 4-byte words)
constexpr int OFF_PKVAL  = 0;                       // float[CAP]  peak values
constexpr int OFF_PKIDX  = CAP;                     // int[CAP]    peak flat indices
constexpr int OFF_HIST   = 2 * CAP;                 // int[NBINS]
constexpr int OFF_CUTBIN = OFF_HIST + NBINS;        // int
constexpr int OFF_PCOUNT = OFF_CUTBIN + 1;          // int (peak count)
constexpr int OFF_CCOUNT = OFF_PCOUNT + 1;          // int (candidate count)
constexpr int OFF_FNUM   = OFF_CCOUNT + 1;          // float[K]
constexpr int OFF_FDEN   = OFF_FNUM + K;            // float[K]
constexpr int OFF_CVAL   = OFF_FDEN + K;            // float[MAXCAND]
constexpr int OFF_CIDX   = OFF_CVAL + MAXCAND;      // int[MAXCAND]
constexpr int OFF_TSCORE = OFF_CIDX + MAXCAND;      // float[K]
constexpr int OFF_TSPAT  = OFF_TSCORE + K;          // int[K]
constexpr int OFF_TCAT   = OFF_TSPAT + K;           // int[K]
constexpr int OFF_A      = (OFF_TCAT + K + 3) & ~3; // float[D*KP], At[d][52], 16B-aligned
constexpr int WS_END     = OFF_A + KP * D;
// contiguous zero-init region: HIST..FDEN
constexpr int ZERO_WORDS = NBINS + 3 + 2 * K;       // 4199

// compile-safe repetition for the 13 float4 accumulators
#define REP13(X) X(0) X(1) X(2) X(3) X(4) X(5) X(6) X(7) X(8) X(9) X(10) X(11) X(12)

__device__ __forceinline__ float sigmoidf(float x) {
    return 1.0f / (1.0f + expf(-x));
}

__device__ __forceinline__ int value_bin(float v) {
    int b = (int)(v * (float)NBINS);
    return b > NBINS - 1 ? NBINS - 1 : b;
}

// ---------------- fused peak detection ----------------
// One block = 64x4 tile of one class. Stages sigmoid (2-halo) then centers
// (1-halo) in LDS, does the 3x3 peak test from LDS, histograms into a LDS
// 4096-bin hist (flushed pre-aggregated), and compact-appends all peaks with
// ONE global atomic per block. Replaces centers/hist/old-gather's ~77 MB of
// latency-bound HBM round trips with a single coalesced read of x.
constexpr int TW = 64, TH = 4;        // tile dims (w x h)
constexpr int SW = TW + 4, SH = TH + 4;   // sigmoid stage with 2-halo: 68 x 8
constexpr int CW = TW + 2, CH2 = TH + 2;  // centers with 1-halo: 66 x 6

__global__ __launch_bounds__(256) void peaks_kernel(
        const float* __restrict__ x, float* __restrict__ ws) {
    __shared__ float ssig[SH][SW];    // 8.7 KB
    __shared__ float scen[CH2][CW];   // 1.6 KB
    __shared__ int   shist[NBINS];    // 16 KB
    __shared__ int   wcnt[4];
    __shared__ int   bbase;

    const int tid = threadIdx.x;
    for (int i = tid; i < NBINS; i += 256) shist[i] = 0;

    const int b  = blockIdx.x;        // 80 classes * 128 tiles
    const int c  = b >> 7;
    const int t  = b & 127;
    const int h0 = (t >> 2) * TH;     // 32 tiles vertically
    const int w0 = (t & 3) * TW;      // 4 tiles horizontally
    const float* xc = x + c * HW;

    // stage sigmoid with 2-halo; out-of-image -> 0 (zero-pad for avg)
    for (int l = tid; l < SH * SW; l += 256) {
        int r = l / SW, q = l - r * SW;
        int h = h0 + r - 2, w = w0 + q - 2;
        float s = 0.0f;
        if ((unsigned)h < (unsigned)H && (unsigned)w < (unsigned)W)
            s = sigmoidf(xc[(h << 8) + w]);
        ssig[r][q] = s;
    }
    __syncthreads();

    // centers with 1-halo; out-of-image -> -inf (max-pool pad)
    // raster-order 3x3 sum with +0.0 for pad == previous kernel's math bitwise
    for (int l = tid; l < CH2 * CW; l += 256) {
        int r = l / CW, q = l - r * CW;
        int h = h0 + r - 1, w = w0 + q - 1;
        float cv = -INFINITY;
        if ((unsigned)h < (unsigned)H && (unsigned)w < (unsigned)W) {
            float s0 = ssig[r + 1][q + 1];
            float sum = 0.0f;
            #pragma unroll
            for (int dh = 0; dh < 3; dh++)
                #pragma unroll
                for (int dw = 0; dw < 3; dw++)
                    sum += ssig[r + dh][q + dw];
            cv = 0.5f * (s0 + sum / 9.0f);
        }
        scen[r][q] = cv;
    }
    __syncthreads();

    // peak test for own pixel (always in-image: tiles cover exactly)
    const int dw = tid & 63, dh = tid >> 6;
    float c0 = scen[dh + 1][dw + 1];
    float m = c0;
    #pragma unroll
    for (int i = 0; i < 3; i++)
        #pragma unroll
        for (int j = 0; j < 3; j++)
            m = fmaxf(m, scen[dh + i][dw + j]);
    const bool peak = (c0 == m);
    const int idx = c * HW + ((h0 + dh) << 8) + (w0 + dw);

    if (peak) atomicAdd(&shist[value_bin(c0)], 1);

    // compact append: ballot -> per-wave exclusive scan -> one atomic per block
    unsigned long long mk = __ballot(peak);
    const int lane = tid & 63, wv = tid >> 6;
    if (lane == 0) wcnt[wv] = __popcll(mk);
    __syncthreads();
    if (tid == 0) {
        int e0 = wcnt[0], e1 = wcnt[1], e2 = wcnt[2], e3 = wcnt[3];
        wcnt[0] = 0; wcnt[1] = e0; wcnt[2] = e0 + e1; wcnt[3] = e0 + e1 + e2;
        bbase = atomicAdd((int*)ws + OFF_PCOUNT, e0 + e1 + e2 + e3);
    }
    __syncthreads();
    if (peak) {
        int pos = bbase + wcnt[wv] + __popcll(mk & ((1ull << lane) - 1ull));
        if (pos < CAP) {
            ws[OFF_PKVAL + pos] = c0;
            ((int*)ws)[OFF_PKIDX + pos] = idx;
        }
    }

    // flush LDS hist, pre-aggregated (only ~#peaks nonzero bins per block)
    __syncthreads();
    for (int i = tid; i < NBINS; i += 256) {
        int v = shist[i];
        if (v) atomicAdd((int*)ws + OFF_HIST + i, v);
    }
}

// ---------------- suffix-scan histogram to find the rank-50 cutoff bin --------
__global__ void scan_kernel(float* ws) {
    __shared__ int chunk[256];
    const int* hist = (const int*)ws + OFF_HIST;
    int t = threadIdx.x;
    int s = 0;
    #pragma unroll
    for (int b = t * 16; b < t * 16 + 16; b++) s += hist[b];
    chunk[t] = s;
    __syncthreads();
    if (t == 0) {
        int cum = 0, cutbin = 0;
        bool found = false;
        for (int ch = 255; ch >= 0 && !found; ch--) {
            if (cum + chunk[ch] >= K) {
                for (int b = ch * 16 + 15; b >= ch * 16; b--) {
                    cum += hist[b];
                    if (cum >= K) { cutbin = b; found = true; break; }
                }
            } else {
                cum += chunk[ch];
            }
        }
        ((int*)ws)[OFF_CUTBIN] = found ? cutbin : 0;
    }
}

// ---------------- gather candidates with bin >= cutoff from the compact list --
__global__ void gather_kernel(float* ws) {
    int q = blockIdx.x * 256 + threadIdx.x;
    int n = ((const int*)ws)[OFF_PCOUNT];
    if (n > CAP) n = CAP;
    if (q >= n) return;
    float v = ws[OFF_PKVAL + q];
    int cutbin = ((const int*)ws)[OFF_CUTBIN];
    if (value_bin(v) >= cutbin) {
        int pos = atomicAdd((int*)ws + OFF_CCOUNT, 1);
        if (pos < MAXCAND) {
            ws[OFF_CVAL + pos] = v;
            ((int*)ws)[OFF_CIDX + pos] = ((const int*)ws)[OFF_PKIDX + q];
        }
    }
}

// ---------------- single-wave top-50 selection (value desc, index asc) --------
__global__ void select_kernel(float* ws) {
    __shared__ float sv[SEL_CAP];
    __shared__ int   si[SEL_CAP];
    __shared__ unsigned smask[MAXCAND / 32];   // 1 = already selected
    const float* cval = ws + OFF_CVAL;
    const int*   cidx = (const int*)ws + OFF_CIDX;
    int n = ((const int*)ws)[OFF_CCOUNT];
    if (n > MAXCAND) n = MAXCAND;
    int t = threadIdx.x;   // 64 threads = one wave

    int cap = n < SEL_CAP ? n : SEL_CAP;
    for (int q = t; q < cap; q += 64) { sv[q] = cval[q]; si[q] = cidx[q]; }
    for (int q = t; q < MAXCAND / 32; q += 64) smask[q] = 0u;
    __syncthreads();

    for (int j = 0; j < K; j++) {
        float bv = -1e30f; int bi = 0x7fffffff; int bp = -1;
        for (int q = t; q < n; q += 64) {
            if (smask[q >> 5] & (1u << (q & 31))) continue;
            float v; int id;
            if (q < SEL_CAP) { v = sv[q]; id = si[q]; }
            else             { v = cval[q]; id = cidx[q]; }
            if (v > bv || (v == bv && id < bi)) { bv = v; bi = id; bp = q; }
        }
        #pragma unroll
        for (int m = 1; m < 64; m <<= 1) {
            float ov = __shfl_xor(bv, m);
            int   oi = __shfl_xor(bi, m);
            int   op = __shfl_xor(bp, m);
            if (ov > bv || (ov == bv && oi < bi)) { bv = ov; bi = oi; bp = op; }
        }
        if (t == 0) {
            float score = (bp >= 0) ? bv : 0.0f;
            int   idx   = (bp >= 0) ? bi : 0;
            ws[OFF_TSCORE + j] = score;
            ((int*)ws)[OFF_TSPAT + j] = idx & (HW - 1);
            ((int*)ws)[OFF_TCAT + j]  = idx >> 15;        // idx / HW
            if (bp >= 0) smask[bp >> 5] |= (1u << (bp & 31));
        }
        __syncthreads();
    }
}

// ---------------- gather kernel vectors, TRANSPOSED: At[d][k] = ksp[d][spatial_k]
// grid = KP (52): k columns 50,51 are zero padding (d_ws is poisoned every call).
// Row stride 52 floats = 208 B = 13 aligned float4s (OFF_A is 16B-aligned).
__global__ void gatherA_kernel(const float* __restrict__ ksp, float* __restrict__ ws) {
    int k = blockIdx.x;     // 0..51
    int d = threadIdx.x;    // 256
    float v = 0.0f;
    if (k < K) {
        int sp = ((const int*)ws)[OFF_TSPAT + k];
        v = ksp[d * HW + sp];
    }
    ws[OFF_A + d * KP + k] = v;
}

// ---------------- mask GEMM v2: out[k][n] = sigmoid(At[:,k] . emb[:,n]) -------
// 1 thread = 1 pixel, all 52 k's in 13 named float4 accumulators (fully static
// indexing -> no scratch spill). emb streams from HBM exactly once, coalesced,
// no LDS. A read per d-row as 13 contiguous float4s at a uniform address ->
// scalar/L1-hit loads; 13 loads feed 208 FMAs. 4-row e-prefetch hides latency.
#define FMAROW(i) { const float4 a_ = Arow[i]; \
    c##i.x = fmaf(e, a_.x, c##i.x); \
    c##i.y = fmaf(e, a_.y, c##i.y); \
    c##i.z = fmaf(e, a_.z, c##i.z); \
    c##i.w = fmaf(e, a_.w, c##i.w); }

__global__ __launch_bounds__(256) void gemm_kernel(
        const float* __restrict__ emb,
        const float* __restrict__ At,    // [D][KP], rows 16B-aligned
        float* __restrict__ out) {
    const int n = blockIdx.x * 256 + threadIdx.x;
    const float4* __restrict__ Af = (const float4*)At;   // 13 float4 per d-row

#define DECLC(i) float4 c##i = make_float4(0.0f, 0.0f, 0.0f, 0.0f);
    REP13(DECLC)
#undef DECLC

    const float* __restrict__ ep = emb + n;
    float cur0 = ep[(size_t)0 * NPIX];
    float cur1 = ep[(size_t)1 * NPIX];
    float cur2 = ep[(size_t)2 * NPIX];
    float cur3 = ep[(size_t)3 * NPIX];

    for (int d = 0; d < D - 4; d += 4) {
        const float* q = ep + (size_t)(d + 4) * NPIX;
        float nxt0 = q[0];
        float nxt1 = q[(size_t)1 * NPIX];
        float nxt2 = q[(size_t)2 * NPIX];
        float nxt3 = q[(size_t)3 * NPIX];
        { const float4* Arow = Af + (d + 0) * 13; const float e = cur0; REP13(FMAROW) }
        { const float4* Arow = Af + (d + 1) * 13; const float e = cur1; REP13(FMAROW) }
        { const float4* Arow = Af + (d + 2) * 13; const float e = cur2; REP13(FMAROW) }
        { const float4* Arow = Af + (d + 3) * 13; const float e = cur3; REP13(FMAROW) }
        cur0 = nxt0; cur1 = nxt1; cur2 = nxt2; cur3 = nxt3;
    }
    { const float4* Arow = Af + (D - 4) * 13; const float e = cur0; REP13(FMAROW) }
    { const float4* Arow = Af + (D - 3) * 13; const float e = cur1; REP13(FMAROW) }
    { const float4* Arow = Af + (D - 2) * 13; const float e = cur2; REP13(FMAROW) }
    { const float4* Arow = Af + (D - 1) * 13; const float e = cur3; REP13(FMAROW) }

    float* op = out + n;
#define EPI(i) \
    if (4*(i)+0 < K) op[(size_t)(4*(i)+0) * NPIX] = 1.0f/(1.0f+expf(-c##i.x)); \
    if (4*(i)+1 < K) op[(size_t)(4*(i)+1) * NPIX] = 1.0f/(1.0f+expf(-c##i.y)); \
    if (4*(i)+2 < K) op[(size_t)(4*(i)+2) * NPIX] = 1.0f/(1.0f+expf(-c##i.z)); \
    if (4*(i)+3 < K) op[(size_t)(4*(i)+3) * NPIX] = 1.0f/(1.0f+expf(-c##i.w));
    REP13(EPI)
#undef EPI
}

// ---------------- rescore: fnum[k] = sum(v where v>0.4), fden[k] = count ------
__global__ __launch_bounds__(256) void rescore_kernel(
        const float* __restrict__ masks,
        float* __restrict__ fnum,
        float* __restrict__ fden) {
    const int k = blockIdx.x;
    const float4* mk = (const float4*)(masks + (size_t)k * NPIX);
    float a = 0.0f; float b = 0.0f;
    int base = blockIdx.y * 2048 + threadIdx.x;   // float4 units
    #pragma unroll
    for (int r = 0; r < 8; r++) {
        float4 v = mk[base + r * 256];
        if (v.x > 0.4f) { a += v.x; b += 1.0f; }
        if (v.y > 0.4f) { a += v.y; b += 1.0f; }
        if (v.z > 0.4f) { a += v.z; b += 1.0f; }
        if (v.w > 0.4f) { a += v.w; b += 1.0f; }
    }
    a += __shfl_xor(a, 1);  b += __shfl_xor(b, 1);
    a += __shfl_xor(a, 2);  b += __shfl_xor(b, 2);
    a += __shfl_xor(a, 4);  b += __shfl_xor(b, 4);
    a += __shfl_xor(a, 8);  b += __shfl_xor(b, 8);
    a += __shfl_xor(a, 16); b += __shfl_xor(b, 16);
    a += __shfl_xor(a, 32); b += __shfl_xor(b, 32);
    __shared__ float sa[4], sb[4];
    int wave = threadIdx.x >> 6;
    if ((threadIdx.x & 63) == 0) { sa[wave] = a; sb[wave] = b; }
    __syncthreads();
    if (threadIdx.x == 0) {
        atomicAdd(&fnum[k], sa[0] + sa[1] + sa[2] + sa[3]);
        atomicAdd(&fden[k], sb[0] + sb[1] + sb[2] + sb[3]);
    }
}

// ---------------- finalize: scores & cats ----------------
__global__ void finalize_kernel(const float* __restrict__ ws, float* __restrict__ out) {
    int j = threadIdx.x;
    if (j < K) {
        float s = ws[OFF_TSCORE + j];
        float num = ws[OFF_FNUM + j];
        float den = ws[OFF_FDEN + j];
        float factor = num / fmaxf(den, 1e-8f);
        float valid = (s > 0.1f) ? 1.0f : 0.0f;
        out[MASK_ELEMS + j]     = s * factor * valid;
        out[MASK_ELEMS + K + j] = (float)(((const int*)ws)[OFF_TCAT + j]);
    }
}

extern "C" void kernel_launch(void* const* d_in, const int* in_sizes, int n_in,
                              void* d_out, int out_size, void* d_ws, size_t ws_size,
                              hipStream_t stream) {
    const float* thing_map = (const float*)d_in[0];
    const float* ksp       = (const float*)d_in[1];
    const float* emb       = (const float*)d_in[2];
    float* out = (float*)d_out;
    float* ws  = (float*)d_ws;

    // zero the atomic-accumulated region (HIST..FDEN contiguous)
    hipMemsetAsync(ws + OFF_HIST, 0, (size_t)ZERO_WORDS * 4, stream);

    peaks_kernel<<<C * 128, 256, 0, stream>>>(thing_map, ws);
    scan_kernel<<<1, 256, 0, stream>>>(ws);
    gather_kernel<<<CAP / 256, 256, 0, stream>>>(ws);
    select_kernel<<<1, 64, 0, stream>>>(ws);
    gatherA_kernel<<<KP, D, 0, stream>>>(ksp, ws);
    gemm_kernel<<<NPIX / 256, 256, 0, stream>>>(emb, ws + OFF_A, out);
    rescore_kernel<<<dim3(K, 16), 256, 0, stream>>>(out, ws + OFF_FNUM, ws + OFF_FDEN);
    finalize_kernel<<<1, 64, 0, stream>>>(ws, out);
}

// Round 3
// 376.792 us; speedup vs baseline: 1.1845x; 1.1845x over previous
//
#include <hip/hip_runtime.h>
#include <hip/hip_bf16.h>
#include <math.h>

// Problem dims (fixed by reference):
//   thing_map   [1, 80, 128, 256]  fp32
//   kernel_space[1,256, 128, 256]  fp32
//   embeddings  [1,256, 256, 512]  fp32
// Outputs (concat, fp32): thing_masks [1,50,256,512] | scores [1,50] | cats [1,50]

constexpr int C   = 80;
constexpr int H   = 128;
constexpr int W   = 256;
constexpr int HW  = H * W;            // 32768
constexpr int CHW = C * HW;           // 2,621,440
constexpr int D   = 256;
constexpr int NPIX = 256 * 512;       // 131072
constexpr int K   = 50;
constexpr int KP  = 52;               // padded k count (13 float4 per d-row)
constexpr int NBINS = 4096;
constexpr int NREP  = 16;             // histogram replicas (hot-line decongestion)
constexpr int MAXCAND = 8192;
constexpr int SEL_CAP = 4096;
constexpr int MASK_ELEMS = K * NPIX;  // 6,553,600

constexpr int NBLK  = C * 128;        // 10240 peak blocks (64x4 tiles)
constexpr int SLOTS = 64;             // max strict 3x3-maxima in a 4x64 tile
constexpr int CAP   = NBLK * SLOTS;   // 655,360

// ws layout (units: 4-byte words)
constexpr int OFF_PKVAL  = 0;                        // float[CAP]  peak values
constexpr int OFF_PKIDX  = CAP;                      // int[CAP]    peak flat indices
constexpr int OFF_PKCNT  = 2 * CAP;                  // int[NBLK]   per-block counts
constexpr int OFF_HIST   = OFF_PKCNT + NBLK;         // int[NREP*NBINS]
constexpr int OFF_CUTBIN = OFF_HIST + NREP * NBINS;  // int
constexpr int OFF_CCOUNT = OFF_CUTBIN + 1;           // int (candidate count)
constexpr int OFF_FNUM   = OFF_CCOUNT + 1;           // float[K]
constexpr int OFF_FDEN   = OFF_FNUM + K;             // float[K]
constexpr int OFF_CVAL   = OFF_FDEN + K;             // float[MAXCAND]
constexpr int OFF_CIDX   = OFF_CVAL + MAXCAND;       // int[MAXCAND]
constexpr int OFF_TSCORE = OFF_CIDX + MAXCAND;       // float[K]
constexpr int OFF_TSPAT  = OFF_TSCORE + K;           // int[K]
constexpr int OFF_TCAT   = OFF_TSPAT + K;            // int[K]
constexpr int OFF_A      = (OFF_TCAT + K + 3) & ~3;  // float[D*KP], At[d][52], 16B-aligned
// contiguous zero-init region: HIST..FDEN (CUTBIN/CCOUNT/FNUM/FDEN ride along)
constexpr int ZERO_WORDS = NREP * NBINS + 2 + 2 * K;

// compile-safe repetition for the 13 float4 accumulators
#define REP13(X) X(0) X(1) X(2) X(3) X(4) X(5) X(6) X(7) X(8) X(9) X(10) X(11) X(12)

__device__ __forceinline__ float sigmoidf(float x) {
    return 1.0f / (1.0f + expf(-x));
}

__device__ __forceinline__ int value_bin(float v) {
    int b = (int)(v * (float)NBINS);
    return b > NBINS - 1 ? NBINS - 1 : b;
}

// ---------------- fused peak detection ----------------
// One block = 64x4 tile of one class. Stages sigmoid (2-halo) then centers
// (1-halo) in LDS, 3x3 peak test from LDS. Output via per-block FIXED slots
// (ballot+popcount rank, plain store of cnt[b]) -- zero global atomics on the
// compaction path. Histogram atomics go to a 16-way replicated global hist to
// kill same-line L2 serialization (4096 int bins = 128 lines; ~290K clustered
// adds previously serialized on a few slices = the 100+ us mystery stall).
constexpr int TW = 64, TH = 4;            // tile dims (w x h)
constexpr int SW = TW + 4, SH = TH + 4;   // sigmoid stage with 2-halo: 68 x 8
constexpr int CW = TW + 2, CH2 = TH + 2;  // centers with 1-halo: 66 x 6

__global__ __launch_bounds__(256) void peaks_kernel(
        const float* __restrict__ x, float* __restrict__ ws) {
    __shared__ float ssig[SH][SW];    // 2.2 KB
    __shared__ float scen[CH2][CW];   // 1.6 KB
    __shared__ int   wcnt[4];

    const int tid = threadIdx.x;
    const int b  = blockIdx.x;        // 80 classes * 128 tiles
    const int c  = b >> 7;
    const int t  = b & 127;
    const int h0 = (t >> 2) * TH;     // 32 tiles vertically
    const int w0 = (t & 3) * TW;      // 4 tiles horizontally
    const float* xc = x + c * HW;

    // stage sigmoid with 2-halo; out-of-image -> 0 (zero-pad for avg)
    for (int l = tid; l < SH * SW; l += 256) {
        int r = l / SW, q = l - r * SW;
        int h = h0 + r - 2, w = w0 + q - 2;
        float s = 0.0f;
        if ((unsigned)h < (unsigned)H && (unsigned)w < (unsigned)W)
            s = sigmoidf(xc[(h << 8) + w]);
        ssig[r][q] = s;
    }
    __syncthreads();

    // centers with 1-halo; out-of-image -> -inf (max-pool pad)
    // raster-order 3x3 sum with +0.0 for pad == monolithic kernel's math bitwise
    for (int l = tid; l < CH2 * CW; l += 256) {
        int r = l / CW, q = l - r * CW;
        int h = h0 + r - 1, w = w0 + q - 1;
        float cv = -INFINITY;
        if ((unsigned)h < (unsigned)H && (unsigned)w < (unsigned)W) {
            float s0 = ssig[r + 1][q + 1];
            float sum = 0.0f;
            #pragma unroll
            for (int dh = 0; dh < 3; dh++)
                #pragma unroll
                for (int dw = 0; dw < 3; dw++)
                    sum += ssig[r + dh][q + dw];
            cv = 0.5f * (s0 + sum / 9.0f);
        }
        scen[r][q] = cv;
    }
    __syncthreads();

    // peak test for own pixel (always in-image: tiles cover exactly)
    const int dw = tid & 63, dh = tid >> 6;
    float c0 = scen[dh + 1][dw + 1];
    float m = c0;
    #pragma unroll
    for (int i = 0; i < 3; i++)
        #pragma unroll
        for (int j = 0; j < 3; j++)
            m = fmaxf(m, scen[dh + i][dw + j]);
    const bool peak = (c0 == m);
    const int idx = c * HW + ((h0 + dh) << 8) + (w0 + dw);

    // replicated histogram: block's replica = b & 15
    if (peak) {
        atomicAdd((int*)ws + OFF_HIST + (b & (NREP - 1)) * NBINS + value_bin(c0), 1);
    }

    // compact into per-block fixed slots: ballot -> rank; no global atomics
    unsigned long long mk = __ballot(peak);
    const int lane = tid & 63, wv = tid >> 6;
    if (lane == 0) wcnt[wv] = __popcll(mk);
    __syncthreads();
    int woff = 0;
    #pragma unroll
    for (int i = 0; i < 4; i++) if (i < wv) woff += wcnt[i];
    if (peak) {
        int rank = woff + __popcll(mk & ((1ull << lane) - 1ull));
        if (rank < SLOTS) {
            ws[OFF_PKVAL + b * SLOTS + rank] = c0;
            ((int*)ws)[OFF_PKIDX + b * SLOTS + rank] = idx;
        }
    }
    if (tid == 0) {
        int total = wcnt[0] + wcnt[1] + wcnt[2] + wcnt[3];
        ((int*)ws)[OFF_PKCNT + b] = total > SLOTS ? SLOTS : total;
    }
}

// ---------------- suffix-scan histogram to find the rank-50 cutoff bin --------
__global__ void scan_kernel(float* ws) {
    __shared__ int shist[NBINS];
    __shared__ int chunk[256];
    const int* hist = (const int*)ws + OFF_HIST;
    int t = threadIdx.x;
    // sum the 16 replicas into LDS (parallel across threads)
    for (int b = t; b < NBINS; b += 256) {
        int s = 0;
        #pragma unroll
        for (int r = 0; r < NREP; r++) s += hist[r * NBINS + b];
        shist[b] = s;
    }
    __syncthreads();
    int s = 0;
    #pragma unroll
    for (int b = t * 16; b < t * 16 + 16; b++) s += shist[b];
    chunk[t] = s;
    __syncthreads();
    if (t == 0) {
        int cum = 0, cutbin = 0;
        bool found = false;
        for (int ch = 255; ch >= 0 && !found; ch--) {
            if (cum + chunk[ch] >= K) {
                for (int b = ch * 16 + 15; b >= ch * 16; b--) {
                    cum += shist[b];
                    if (cum >= K) { cutbin = b; found = true; break; }
                }
            } else {
                cum += chunk[ch];
            }
        }
        ((int*)ws)[OFF_CUTBIN] = found ? cutbin : 0;
    }
}

// ---------------- gather candidates with bin >= cutoff from the slot lists ----
__global__ void gather_kernel(float* ws) {
    int q = blockIdx.x * 256 + threadIdx.x;   // grid = CAP/256
    int bid = q >> 6;                          // wave-uniform -> scalar load
    int i = q & 63;
    int cnt = ((const int*)ws)[OFF_PKCNT + bid];
    if (i < cnt) {
        float v = ws[OFF_PKVAL + q];
        int cutbin = ((const int*)ws)[OFF_CUTBIN];
        if (value_bin(v) >= cutbin) {
            int pos = atomicAdd((int*)ws + OFF_CCOUNT, 1);
            if (pos < MAXCAND) {
                ws[OFF_CVAL + pos] = v;
                ((int*)ws)[OFF_CIDX + pos] = ((const int*)ws)[OFF_PKIDX + q];
            }
        }
    }
}

// ---------------- single-wave top-50 selection (value desc, index asc) --------
__global__ void select_kernel(float* ws) {
    __shared__ float sv[SEL_CAP];
    __shared__ int   si[SEL_CAP];
    __shared__ unsigned smask[MAXCAND / 32];   // 1 = already selected
    const float* cval = ws + OFF_CVAL;
    const int*   cidx = (const int*)ws + OFF_CIDX;
    int n = ((const int*)ws)[OFF_CCOUNT];
    if (n > MAXCAND) n = MAXCAND;
    int t = threadIdx.x;   // 64 threads = one wave

    int cap = n < SEL_CAP ? n : SEL_CAP;
    for (int q = t; q < cap; q += 64) { sv[q] = cval[q]; si[q] = cidx[q]; }
    for (int q = t; q < MAXCAND / 32; q += 64) smask[q] = 0u;
    __syncthreads();

    for (int j = 0; j < K; j++) {
        float bv = -1e30f; int bi = 0x7fffffff; int bp = -1;
        for (int q = t; q < n; q += 64) {
            if (smask[q >> 5] & (1u << (q & 31))) continue;
            float v; int id;
            if (q < SEL_CAP) { v = sv[q]; id = si[q]; }
            else             { v = cval[q]; id = cidx[q]; }
            if (v > bv || (v == bv && id < bi)) { bv = v; bi = id; bp = q; }
        }
        #pragma unroll
        for (int m = 1; m < 64; m <<= 1) {
            float ov = __shfl_xor(bv, m);
            int   oi = __shfl_xor(bi, m);
            int   op = __shfl_xor(bp, m);
            if (ov > bv || (ov == bv && oi < bi)) { bv = ov; bi = oi; bp = op; }
        }
        if (t == 0) {
            float score = (bp >= 0) ? bv : 0.0f;
            int   idx   = (bp >= 0) ? bi : 0;
            ws[OFF_TSCORE + j] = score;
            ((int*)ws)[OFF_TSPAT + j] = idx & (HW - 1);
            ((int*)ws)[OFF_TCAT + j]  = idx >> 15;        // idx / HW
            if (bp >= 0) smask[bp >> 5] |= (1u << (bp & 31));
        }
        __syncthreads();
    }
}

// ---------------- gather kernel vectors, TRANSPOSED: At[d][k] = ksp[d][spatial_k]
// grid = KP (52): k columns 50,51 are zero padding (d_ws is poisoned every call).
// Row stride 52 floats = 208 B = 13 aligned float4s (OFF_A is 16B-aligned).
__global__ void gatherA_kernel(const float* __restrict__ ksp, float* __restrict__ ws) {
    int k = blockIdx.x;     // 0..51
    int d = threadIdx.x;    // 256
    float v = 0.0f;
    if (k < K) {
        int sp = ((const int*)ws)[OFF_TSPAT + k];
        v = ksp[d * HW + sp];
    }
    ws[OFF_A + d * KP + k] = v;
}

// ---------------- mask GEMM v2: out[k][n] = sigmoid(At[:,k] . emb[:,n]) -------
// 1 thread = 1 pixel, all 52 k's in 13 named float4 accumulators (fully static
// indexing -> no scratch spill). emb streams from HBM exactly once, coalesced,
// no LDS. A read per d-row as 13 contiguous float4s at a uniform address ->
// scalar/L1-hit loads; 13 loads feed 208 FMAs. 4-row e-prefetch hides latency.
#define FMAROW(i) { const float4 a_ = Arow[i]; \
    c##i.x = fmaf(e, a_.x, c##i.x); \
    c##i.y = fmaf(e, a_.y, c##i.y); \
    c##i.z = fmaf(e, a_.z, c##i.z); \
    c##i.w = fmaf(e, a_.w, c##i.w); }

__global__ __launch_bounds__(256) void gemm_kernel(
        const float* __restrict__ emb,
        const float* __restrict__ At,    // [D][KP], rows 16B-aligned
        float* __restrict__ out) {
    const int n = blockIdx.x * 256 + threadIdx.x;
    const float4* __restrict__ Af = (const float4*)At;   // 13 float4 per d-row

#define DECLC(i) float4 c##i = make_float4(0.0f, 0.0f, 0.0f, 0.0f);
    REP13(DECLC)
#undef DECLC

    const float* __restrict__ ep = emb + n;
    float cur0 = ep[(size_t)0 * NPIX];
    float cur1 = ep[(size_t)1 * NPIX];
    float cur2 = ep[(size_t)2 * NPIX];
    float cur3 = ep[(size_t)3 * NPIX];

    for (int d = 0; d < D - 4; d += 4) {
        const float* q = ep + (size_t)(d + 4) * NPIX;
        float nxt0 = q[0];
        float nxt1 = q[(size_t)1 * NPIX];
        float nxt2 = q[(size_t)2 * NPIX];
        float nxt3 = q[(size_t)3 * NPIX];
        { const float4* Arow = Af + (d + 0) * 13; const float e = cur0; REP13(FMAROW) }
        { const float4* Arow = Af + (d + 1) * 13; const float e = cur1; REP13(FMAROW) }
        { const float4* Arow = Af + (d + 2) * 13; const float e = cur2; REP13(FMAROW) }
        { const float4* Arow = Af + (d + 3) * 13; const float e = cur3; REP13(FMAROW) }
        cur0 = nxt0; cur1 = nxt1; cur2 = nxt2; cur3 = nxt3;
    }
    { const float4* Arow = Af + (D - 4) * 13; const float e = cur0; REP13(FMAROW) }
    { const float4* Arow = Af + (D - 3) * 13; const float e = cur1; REP13(FMAROW) }
    { const float4* Arow = Af + (D - 2) * 13; const float e = cur2; REP13(FMAROW) }
    { const float4* Arow = Af + (D - 1) * 13; const float e = cur3; REP13(FMAROW) }

    float* op = out + n;
#define EPI(i) \
    if (4*(i)+0 < K) op[(size_t)(4*(i)+0) * NPIX] = 1.0f/(1.0f+expf(-c##i.x)); \
    if (4*(i)+1 < K) op[(size_t)(4*(i)+1) * NPIX] = 1.0f/(1.0f+expf(-c##i.y)); \
    if (4*(i)+2 < K) op[(size_t)(4*(i)+2) * NPIX] = 1.0f/(1.0f+expf(-c##i.z)); \
    if (4*(i)+3 < K) op[(size_t)(4*(i)+3) * NPIX] = 1.0f/(1.0f+expf(-c##i.w));
    REP13(EPI)
#undef EPI
}

// ---------------- rescore: fnum[k] = sum(v where v>0.4), fden[k] = count ------
__global__ __launch_bounds__(256) void rescore_kernel(
        const float* __restrict__ masks,
        float* __restrict__ fnum,
        float* __restrict__ fden) {
    const int k = blockIdx.x;
    const float4* mk = (const float4*)(masks + (size_t)k * NPIX);
    float a = 0.0f; float b = 0.0f;
    int base = blockIdx.y * 2048 + threadIdx.x;   // float4 units
    #pragma unroll
    for (int r = 0; r < 8; r++) {
        float4 v = mk[base + r * 256];
        if (v.x > 0.4f) { a += v.x; b += 1.0f; }
        if (v.y > 0.4f) { a += v.y; b += 1.0f; }
        if (v.z > 0.4f) { a += v.z; b += 1.0f; }
        if (v.w > 0.4f) { a += v.w; b += 1.0f; }
    }
    a += __shfl_xor(a, 1);  b += __shfl_xor(b, 1);
    a += __shfl_xor(a, 2);  b += __shfl_xor(b, 2);
    a += __shfl_xor(a, 4);  b += __shfl_xor(b, 4);
    a += __shfl_xor(a, 8);  b += __shfl_xor(b, 8);
    a += __shfl_xor(a, 16); b += __shfl_xor(b, 16);
    a += __shfl_xor(a, 32); b += __shfl_xor(b, 32);
    __shared__ float sa[4], sb[4];
    int wave = threadIdx.x >> 6;
    if ((threadIdx.x & 63) == 0) { sa[wave] = a; sb[wave] = b; }
    __syncthreads();
    if (threadIdx.x == 0) {
        atomicAdd(&fnum[k], sa[0] + sa[1] + sa[2] + sa[3]);
        atomicAdd(&fden[k], sb[0] + sb[1] + sb[2] + sb[3]);
    }
}

// ---------------- finalize: scores & cats ----------------
__global__ void finalize_kernel(const float* __restrict__ ws, float* __restrict__ out) {
    int j = threadIdx.x;
    if (j < K) {
        float s = ws[OFF_TSCORE + j];
        float num = ws[OFF_FNUM + j];
        float den = ws[OFF_FDEN + j];
        float factor = num / fmaxf(den, 1e-8f);
        float valid = (s > 0.1f) ? 1.0f : 0.0f;
        out[MASK_ELEMS + j]     = s * factor * valid;
        out[MASK_ELEMS + K + j] = (float)(((const int*)ws)[OFF_TCAT + j]);
    }
}

extern "C" void kernel_launch(void* const* d_in, const int* in_sizes, int n_in,
                              void* d_out, int out_size, void* d_ws, size_t ws_size,
                              hipStream_t stream) {
    const float* thing_map = (const float*)d_in[0];
    const float* ksp       = (const float*)d_in[1];
    const float* emb       = (const float*)d_in[2];
    float* out = (float*)d_out;
    float* ws  = (float*)d_ws;

    // zero the atomic-accumulated region (HIST..FDEN contiguous, 256 KB)
    hipMemsetAsync(ws + OFF_HIST, 0, (size_t)ZERO_WORDS * 4, stream);

    peaks_kernel<<<NBLK, 256, 0, stream>>>(thing_map, ws);
    scan_kernel<<<1, 256, 0, stream>>>(ws);
    gather_kernel<<<CAP / 256, 256, 0, stream>>>(ws);
    select_kernel<<<1, 64, 0, stream>>>(ws);
    gatherA_kernel<<<KP, D, 0, stream>>>(ksp, ws);
    gemm_kernel<<<NPIX / 256, 256, 0, stream>>>(emb, ws + OFF_A, out);
    rescore_kernel<<<dim3(K, 16), 256, 0, stream>>>(out, ws + OFF_FNUM, ws + OFF_FDEN);
    finalize_kernel<<<1, 64, 0, stream>>>(ws, out);
}